// Round 1
// baseline (200.859 us; speedup 1.0000x reference)
//
#include <hip/hip_runtime.h>
#include <hip/hip_bf16.h>

typedef __bf16 bf16x8 __attribute__((ext_vector_type(8)));
typedef __bf16 bf16x4 __attribute__((ext_vector_type(4)));
typedef float  f32x4  __attribute__((ext_vector_type(4)));

#define HID   256
#define BM    64
#define PITCH 264   // bf16 elems per LDS row: 256 + 8 pad -> breaks 512B-stride bank conflict

// ---- pre-pack the 5 weight matrices fp32 -> bf16 into workspace -------------
__global__ void __launch_bounds__(256) prepack_weights(
    const float* __restrict__ w0, const float* __restrict__ w1,
    const float* __restrict__ w2, const float* __restrict__ w3,
    const float* __restrict__ w4, __bf16* __restrict__ wb)
{
    int e    = (blockIdx.x * 256 + threadIdx.x) * 4;   // over 5*65536 elements
    int gate = e >> 16;
    int rem  = e & 65535;
    const float* src = gate == 0 ? w0 : gate == 1 ? w1 : gate == 2 ? w2
                     : gate == 3 ? w3 : w4;
    float4 v = *(const float4*)(src + rem);
    bf16x4 o;
    o[0] = (__bf16)v.x; o[1] = (__bf16)v.y; o[2] = (__bf16)v.z; o[3] = (__bf16)v.w;
    *(bf16x4*)(wb + e) = o;
}

// ---- fused GRU cell ---------------------------------------------------------
// gates: 0=ir 1=iz 2=in (A = x), 3=hz 4=hn (A = h_prev)
template<bool PACKED>
__global__ void __launch_bounds__(512, 2) gru_fused(
    const float* __restrict__ x,  const float* __restrict__ h,
    const __bf16* __restrict__ wb,
    const float* __restrict__ w_ir, const float* __restrict__ w_iz,
    const float* __restrict__ w_in, const float* __restrict__ w_hz,
    const float* __restrict__ w_hn,
    const float* __restrict__ b_ir, const float* __restrict__ b_iz,
    const float* __restrict__ b_in, const float* __restrict__ b_hz,
    const float* __restrict__ b_hn,
    float* __restrict__ out)
{
    __shared__ __bf16 xt[BM * PITCH];
    __shared__ __bf16 ht[BM * PITCH];

    const int t    = threadIdx.x;
    const int row0 = blockIdx.x * BM;

    // ---- stage x,h tiles (fp32 -> bf16) into LDS, coalesced float4 loads ----
#pragma unroll
    for (int i = 0; i < 8; ++i) {
        int c  = i * 512 + t;          // chunk of 4 elems
        int r  = c >> 6;
        int k4 = (c & 63) * 4;
        float4 vx = *(const float4*)(x + (size_t)(row0 + r) * HID + k4);
        float4 vh = *(const float4*)(h + (size_t)(row0 + r) * HID + k4);
        bf16x4 bx, bh;
        bx[0] = (__bf16)vx.x; bx[1] = (__bf16)vx.y; bx[2] = (__bf16)vx.z; bx[3] = (__bf16)vx.w;
        bh[0] = (__bf16)vh.x; bh[1] = (__bf16)vh.y; bh[2] = (__bf16)vh.z; bh[3] = (__bf16)vh.w;
        *(bf16x4*)(xt + r * PITCH + k4) = bx;
        *(bf16x4*)(ht + r * PITCH + k4) = bh;
    }
    __syncthreads();

    const int lane = t & 63;
    const int wid  = t >> 6;
    const int wm   = wid >> 2;    // 0..1  (rows: wm*32)
    const int wn   = wid & 3;     // 0..3  (cols: wn*64)
    const int lr   = lane & 15;
    const int lg   = lane >> 4;   // 0..3

    f32x4 acc[5][2][4];           // [gate][mf][nf]
#pragma unroll
    for (int g = 0; g < 5; ++g)
#pragma unroll
        for (int mf = 0; mf < 2; ++mf)
#pragma unroll
            for (int nf = 0; nf < 4; ++nf)
                acc[g][mf][nf] = (f32x4)0.0f;

    const float* wsrc[5] = { w_ir, w_iz, w_in, w_hz, w_hn };

    // ---- K loop: 8 K-steps of 32, processed in 4 pairs ----------------------
#pragma unroll
    for (int kp = 0; kp < 4; ++kp) {
        bf16x8 ax[2][2], ah[2][2];    // [mf][k2]
#pragma unroll
        for (int mf = 0; mf < 2; ++mf)
#pragma unroll
            for (int k2 = 0; k2 < 2; ++k2) {
                int off = (wm * 32 + mf * 16 + lr) * PITCH + (kp * 2 + k2) * 32 + lg * 8;
                ax[mf][k2] = *(const bf16x8*)(xt + off);
                ah[mf][k2] = *(const bf16x8*)(ht + off);
            }
#pragma unroll
        for (int g = 0; g < 5; ++g) {
#pragma unroll
            for (int k2 = 0; k2 < 2; ++k2) {
#pragma unroll
                for (int nf = 0; nf < 4; ++nf) {
                    int col  = wn * 64 + nf * 16 + lr;
                    int koff = (kp * 2 + k2) * 32 + lg * 8;
                    bf16x8 b;
                    if (PACKED) {
                        b = *(const bf16x8*)(wb + (g << 16) + col * HID + koff);
                    } else {
                        float4 p = *(const float4*)(wsrc[g] + col * HID + koff);
                        float4 q = *(const float4*)(wsrc[g] + col * HID + koff + 4);
                        b[0]=(__bf16)p.x; b[1]=(__bf16)p.y; b[2]=(__bf16)p.z; b[3]=(__bf16)p.w;
                        b[4]=(__bf16)q.x; b[5]=(__bf16)q.y; b[6]=(__bf16)q.z; b[7]=(__bf16)q.w;
                    }
#pragma unroll
                    for (int mf = 0; mf < 2; ++mf) {
                        acc[g][mf][nf] = __builtin_amdgcn_mfma_f32_16x16x32_bf16(
                            g < 3 ? ax[mf][k2] : ah[mf][k2], b, acc[g][mf][nf], 0, 0, 0);
                    }
                }
            }
        }
    }

    // ---- epilogue: gate fusion in registers, write h_new --------------------
    float bb[5][4];
#pragma unroll
    for (int nf = 0; nf < 4; ++nf) {
        int col = wn * 64 + nf * 16 + lr;
        bb[0][nf] = b_ir[col]; bb[1][nf] = b_iz[col]; bb[2][nf] = b_in[col];
        bb[3][nf] = b_hz[col]; bb[4][nf] = b_hn[col];
    }
#pragma unroll
    for (int mf = 0; mf < 2; ++mf)
#pragma unroll
        for (int nf = 0; nf < 4; ++nf)
#pragma unroll
            for (int i = 0; i < 4; ++i) {
                int rl  = wm * 32 + mf * 16 + lg * 4 + i;   // C/D: row=(lane>>4)*4+i
                int col = wn * 64 + nf * 16 + lr;           //      col=lane&15
                float s_ir = acc[0][mf][nf][i] + bb[0][nf];
                float s_iz = acc[1][mf][nf][i] + bb[1][nf];
                float s_in = acc[2][mf][nf][i] + bb[2][nf];
                float s_hz = acc[3][mf][nf][i] + bb[3][nf];
                float s_hn = acc[4][mf][nf][i] + bb[4][nf];
                float z  = 1.0f / (1.0f + __expf(-(s_iz + s_hz)));
                float r  = 1.0f / (1.0f + __expf(-(s_ir + s_hz)));
                float e2 = __expf(2.0f * (s_in + r * s_hn));
                float g  = 1.0f - 2.0f / (e2 + 1.0f);       // tanh
                float hp = (float)ht[rl * PITCH + col];
                out[(size_t)(row0 + rl) * HID + col] = (1.0f - z) * g + z * hp;
            }
}

extern "C" void kernel_launch(void* const* d_in, const int* in_sizes, int n_in,
                              void* d_out, int out_size, void* d_ws, size_t ws_size,
                              hipStream_t stream) {
    const float* x    = (const float*)d_in[0];
    const float* h    = (const float*)d_in[1];
    const float* w_ir = (const float*)d_in[2];
    const float* b_ir = (const float*)d_in[3];
    const float* w_iz = (const float*)d_in[4];
    const float* b_iz = (const float*)d_in[5];
    const float* w_in = (const float*)d_in[6];
    const float* b_in = (const float*)d_in[7];
    const float* w_hz = (const float*)d_in[8];
    const float* b_hz = (const float*)d_in[9];
    const float* w_hn = (const float*)d_in[10];
    const float* b_hn = (const float*)d_in[11];
    float* out = (float*)d_out;

    const int B = in_sizes[0] / HID;           // 65536
    const size_t wb_bytes = (size_t)5 * HID * HID * sizeof(__bf16);  // 640 KB

    if (ws_size >= wb_bytes) {
        __bf16* wb = (__bf16*)d_ws;
        prepack_weights<<<5 * HID * HID / (256 * 4), 256, 0, stream>>>(
            w_ir, w_iz, w_in, w_hz, w_hn, wb);
        gru_fused<true><<<B / BM, 512, 0, stream>>>(
            x, h, wb, nullptr, nullptr, nullptr, nullptr, nullptr,
            b_ir, b_iz, b_in, b_hz, b_hn, out);
    } else {
        gru_fused<false><<<B / BM, 512, 0, stream>>>(
            x, h, nullptr, w_ir, w_iz, w_in, w_hz, w_hn,
            b_ir, b_iz, b_in, b_hz, b_hn, out);
    }
}